// Round 13
// baseline (290.719 us; speedup 1.0000x reference)
//
#include <hip/hip_runtime.h>
#include <hip/hip_bf16.h>

typedef __attribute__((ext_vector_type(4))) float f32x4;
typedef __attribute__((ext_vector_type(8))) short s16x8;
typedef __attribute__((ext_vector_type(4))) short s16x4;
typedef __attribute__((ext_vector_type(4))) int i32x4;

__device__ __forceinline__ short f2bf(float f) {
    union { __hip_bfloat16 h; short s; } u;
    u.h = __float2bfloat16(f);
    return u.s;
}

#define GLD16(g, l) __builtin_amdgcn_global_load_lds((const __attribute__((address_space(1))) void*)(g), (__attribute__((address_space(3))) void*)(l), 16, 0, 0)
#define MFMA16(a, b, c) __builtin_amdgcn_mfma_f32_16x16x32_bf16((a), (b), (c), 0, 0, 0)

// ---------------- conversion kernels ----------------
__global__ void conv_lin(const float* __restrict__ in, short* __restrict__ out, int n4) {
    int i = blockIdx.x * blockDim.x + threadIdx.x;
    int stride = gridDim.x * blockDim.x;
    for (; i < n4; i += stride) {
        float4 v = reinterpret_cast<const float4*>(in)[i];
        s16x4 o;
        o[0] = f2bf(v.x); o[1] = f2bf(v.y); o[2] = f2bf(v.z); o[3] = f2bf(v.w);
        reinterpret_cast<s16x4*>(out)[i] = o;
    }
}

// x[L][N][C] f32 -> Xb[(n*L+l)][C] bf16
__global__ void conv_x(const float* __restrict__ x, short* __restrict__ Xb) {
    const int total = 1024 * 4 * 2048 / 4;
    int i = blockIdx.x * blockDim.x + threadIdx.x;
    int stride = gridDim.x * blockDim.x;
    for (; i < total; i += stride) {
        float4 v = reinterpret_cast<const float4*>(x)[i];
        int c4 = i & 511;          // C/4 = 512
        int n  = (i >> 9) & 3;
        int l  = i >> 11;
        s16x4 o;
        o[0] = f2bf(v.x); o[1] = f2bf(v.y); o[2] = f2bf(v.z); o[3] = f2bf(v.w);
        reinterpret_cast<s16x4*>(Xb)[(n * 1024 + l) * 512 + c4] = o;
    }
}

// cos/sin table for positions W..W+L-1, 64 pair-freqs
__global__ void rope_tab(float* __restrict__ ctab, float* __restrict__ stab) {
    int l = blockIdx.x, t = threadIdx.x;
    float pos = (float)(512 + l);
    float inv = __expf(-9.210340371976184f * ((float)t * (1.0f / 64.0f)));
    float a = pos * inv;
    float s, c;
    sincosf(a, &s, &c);
    ctab[l * 64 + t] = c;
    stab[l * 64 + t] = s;
}

// ======== 256x256 quadrant-phased 8-phase GEMM (gemm_qkv only) ========
// 8 waves (wr=w>>2 in {0,1}: M-half; wc=w&3: N-quarter). Per-wave 128x64, acc[8][4].
// LDS half-region: [128 rows][64 k] bf16, 128B rows, swizzle byte ^= ((row&7)<<4)
// (hardware-verified 0 bank conflicts in r6/r8/r9).
// Phase q computes C-quadrant mi in {2q,2q+1} over full K=64 -> consecutive phases'
// MFMA clusters hit DIFFERENT accumulators (pipeline across the barrier).
// Stages: iter u: ph1,2 -> A(d1, tile 2u+1); ph3,4 -> B(d0, 2u+2);
//                 ph5,6 -> A(d0, 2u+2);     ph7,8 -> B(d1, 2u+3).
// vmcnt(4) at ph4 (confirms tile 2u+1) and ph8 (confirms tile 2u+2). No drain in loop.

__device__ __forceinline__ void stg_half(const short* __restrict__ G, int rowbase, int kt,
                                         short* dst, int tid) {
    #pragma unroll
    for (int q = 0; q < 2; ++q) {
        int chunk = q * 512 + tid;
        int row = chunk >> 3;
        int sc = ((((chunk & 7) << 4) ^ ((row & 7) << 4)) >> 1);   // pre-swizzled elem col
        GLD16(G + (size_t)(rowbase + row) * 2048 + kt + sc, dst + (q * 512 + (tid & ~63)) * 8);
    }
}

__device__ __forceinline__ s16x8 rdf(const short* buf, int row, int ks, int lane) {
    int byte = row * 128 + (((ks << 6) + ((lane >> 4) << 4)) ^ ((row & 7) << 4));
    return *reinterpret_cast<const s16x8*>(reinterpret_cast<const char*>(buf) + byte);
}

#define PH(D, Q, VMN, ...)                                                            \
    {                                                                                  \
        const short* Ah = &Al[D][wr][0];                                               \
        const short* Bh = &Bl[D][wc >> 1][0];                                          \
        if (Q == 0) {                                                                  \
            _Pragma("unroll")                                                          \
            for (int nj = 0; nj < 4; ++nj) {                                           \
                bf[nj][0] = rdf(Bh, (wc & 1) * 64 + nj * 16 + (lane & 15), 0, lane);   \
                bf[nj][1] = rdf(Bh, (wc & 1) * 64 + nj * 16 + (lane & 15), 1, lane);   \
            }                                                                          \
        }                                                                              \
        s16x8 af[2][2];                                                                \
        _Pragma("unroll")                                                              \
        for (int m = 0; m < 2; ++m) {                                                  \
            af[m][0] = rdf(Ah, (Q * 2 + m) * 16 + (lane & 15), 0, lane);               \
            af[m][1] = rdf(Ah, (Q * 2 + m) * 16 + (lane & 15), 1, lane);               \
        }                                                                              \
        __VA_ARGS__;                                                                   \
        if ((VMN) == 4) { asm volatile("s_waitcnt vmcnt(4)" ::: "memory");             \
                          __builtin_amdgcn_sched_barrier(0); }                         \
        if ((VMN) == 0) { asm volatile("s_waitcnt vmcnt(0)" ::: "memory");             \
                          __builtin_amdgcn_sched_barrier(0); }                         \
        __builtin_amdgcn_s_barrier();                                                  \
        asm volatile("s_waitcnt lgkmcnt(0)" ::: "memory");                             \
        __builtin_amdgcn_sched_barrier(0);                                             \
        __builtin_amdgcn_s_setprio(1);                                                 \
        _Pragma("unroll")                                                              \
        for (int m = 0; m < 2; ++m)                                                    \
            _Pragma("unroll")                                                          \
            for (int nj = 0; nj < 4; ++nj) {                                           \
                acc[Q * 2 + m][nj] = MFMA16(af[m][0], bf[nj][0], acc[Q * 2 + m][nj]);  \
                acc[Q * 2 + m][nj] = MFMA16(af[m][1], bf[nj][1], acc[Q * 2 + m][nj]);  \
            }                                                                          \
        __builtin_amdgcn_s_setprio(0);                                                 \
        __builtin_amdgcn_s_barrier();                                                  \
        __builtin_amdgcn_sched_barrier(0);                                             \
    }

// Xb[4096][2048] @ Wqkv[6144][2048]^T ; cols [0,2048)=Q, [2048,4096)=K, [4096,6144)=V
__global__ __launch_bounds__(512, 2)
void gemm_qkv8(const short* __restrict__ Xb, const short* __restrict__ Wqkv,
               const float* __restrict__ bq, const float* __restrict__ bkv,
               const float* __restrict__ ctab, const float* __restrict__ stab,
               short* __restrict__ Qr, short* __restrict__ Kr, short* __restrict__ Vr) {
    __shared__ short Al[2][2][8192];   // 64 KB: [dbuf][M-half][128x64]
    __shared__ short Bl[2][2][8192];   // 64 KB: [dbuf][N-half][128x64]
    const int tid = threadIdx.x, lane = tid & 63, w = tid >> 6;
    const int wr = w >> 2, wc = w & 3;
    const int m0 = blockIdx.y * 256, j0 = blockIdx.x * 256;

    f32x4 acc[8][4];
    #pragma unroll
    for (int a = 0; a < 8; ++a)
        #pragma unroll
        for (int c = 0; c < 4; ++c)
            #pragma unroll
            for (int r = 0; r < 4; ++r) acc[a][c][r] = 0.f;

    // prologue: tile0 A+B (d0) and tile1 B (d1); tile1 A comes from iter0 ph1,2
    stg_half(Xb,   m0,        0, &Al[0][0][0], tid);
    stg_half(Xb,   m0 + 128,  0, &Al[0][1][0], tid);
    stg_half(Wqkv, j0,        0, &Bl[0][0][0], tid);
    stg_half(Wqkv, j0 + 128,  0, &Bl[0][1][0], tid);
    stg_half(Wqkv, j0,       64, &Bl[1][0][0], tid);
    stg_half(Wqkv, j0 + 128, 64, &Bl[1][1][0], tid);
    asm volatile("s_waitcnt vmcnt(4)" ::: "memory");
    __builtin_amdgcn_s_barrier();
    __builtin_amdgcn_sched_barrier(0);

    s16x8 bf[4][2];
    for (int u = 0; u < 16; ++u) {
        const int ka = (2 * u + 1) * 64;
        const int kb = (2 * u + 2) * 64;
        const int kc = (2 * u + 3) * 64;
        const bool s = (u < 15);
        PH(0, 0, -1, stg_half(Xb, m0,       ka, &Al[1][0][0], tid));
        PH(0, 1, -1, stg_half(Xb, m0 + 128, ka, &Al[1][1][0], tid));
        PH(0, 2, -1, if (s) stg_half(Wqkv, j0,       kb, &Bl[0][0][0], tid));
        PH(0, 3, (s ? 4 : 0), if (s) stg_half(Wqkv, j0 + 128, kb, &Bl[0][1][0], tid));
        PH(1, 0, -1, if (s) stg_half(Xb, m0,       kb, &Al[0][0][0], tid));
        PH(1, 1, -1, if (s) stg_half(Xb, m0 + 128, kb, &Al[0][1][0], tid));
        PH(1, 2, -1, if (s) stg_half(Wqkv, j0,       kc, &Bl[1][0][0], tid));
        PH(1, 3, (s ? 4 : 0), if (s) stg_half(Wqkv, j0 + 128, kc, &Bl[1][1][0], tid));
    }
    asm volatile("s_waitcnt vmcnt(0)" ::: "memory");

    // epilogue: bias + RoPE + scatter (per-wave 128x64 at (wr*128, wc*64))
    const int region = j0 >> 11;   // 0:Q 1:K 2:V (256-panels never straddle)
    #pragma unroll
    for (int mi = 0; mi < 8; ++mi) {
        #pragma unroll
        for (int nj = 0; nj < 4; ++nj) {
            int col = j0 + wc * 64 + nj * 16 + (lane & 15);
            int h = (col >> 7) & 15;
            int d = col & 127;
            #pragma unroll
            for (int r = 0; r < 4; ++r) {
                int row = m0 + wr * 128 + mi * 16 + (lane >> 4) * 4 + r;
                int n = row >> 10, l = row & 1023;
                float v = acc[mi][nj][r];
                size_t oidx = (((size_t)(n * 16 + h)) * 1024 + l) * 128 + d;
                if (region == 0) {
                    v += bq[col];
                    float other = __shfl_xor(v, 1, 64);
                    float cs = ctab[l * 64 + (d >> 1)];
                    float sn = stab[l * 64 + (d >> 1)];
                    float o = (d & 1) ? (other * sn + v * cs) : (v * cs - other * sn);
                    Qr[oidx] = f2bf(o * 0.08838834764831843f);   // fold SCALE into Q
                } else if (region == 1) {
                    v += bkv[col - 2048];
                    float other = __shfl_xor(v, 1, 64);
                    float cs = ctab[l * 64 + (d >> 1)];
                    float sn = stab[l * 64 + (d >> 1)];
                    float o = (d & 1) ? (other * sn + v * cs) : (v * cs - other * sn);
                    Kr[oidx] = f2bf(o);
                } else {
                    v += bkv[col - 2048];
                    Vr[oidx] = f2bf(v);
                }
            }
        }
    }
}

// ---------------- 128x128 bf16 GEMM core (round-1/6 verified structure) ----------------
__device__ __forceinline__ void gemm128(const short* __restrict__ A, const short* __restrict__ B,
                                        short* As, short* Bs, f32x4 acc[4][4], int m0, int j0) {
    const int K = 2048;
    const int tid = threadIdx.x;
    const int lane = tid & 63;
    const int w = tid >> 6;
    const int wr = w >> 1, wc = w & 1;
    const int r8 = lane >> 3;
    const int cc = ((lane & 7) ^ r8) << 3;
    const size_t rowA0 = (size_t)(m0 + w * 32 + r8);
    const size_t rowB0 = (size_t)(j0 + w * 32 + r8);
    for (int kt = 0; kt < K; kt += 64) {
        #pragma unroll
        for (int q = 0; q < 4; ++q) {
            GLD16(A + (rowA0 + q * 8) * K + kt + cc, As + (w * 32 + q * 8) * 64);
            GLD16(B + (rowB0 + q * 8) * K + kt + cc, Bs + (w * 32 + q * 8) * 64);
        }
        __syncthreads();
        #pragma unroll
        for (int kk = 0; kk < 2; ++kk) {
            s16x8 af[4], bfv[4];
            #pragma unroll
            for (int mi = 0; mi < 4; ++mi) {
                int row = wr * 64 + mi * 16 + (lane & 15);
                int byte = row * 128 + ((kk * 64 + (lane >> 4) * 16) ^ ((row & 7) << 4));
                af[mi] = *reinterpret_cast<const s16x8*>(reinterpret_cast<const char*>(As) + byte);
            }
            #pragma unroll
            for (int nj = 0; nj < 4; ++nj) {
                int row = wc * 64 + nj * 16 + (lane & 15);
                int byte = row * 128 + ((kk * 64 + (lane >> 4) * 16) ^ ((row & 7) << 4));
                bfv[nj] = *reinterpret_cast<const s16x8*>(reinterpret_cast<const char*>(Bs) + byte);
            }
            #pragma unroll
            for (int mi = 0; mi < 4; ++mi)
                #pragma unroll
                for (int nj = 0; nj < 4; ++nj)
                    acc[mi][nj] = MFMA16(af[mi], bfv[nj], acc[mi][nj]);
        }
        __syncthreads();
    }
}

// ---------------- output GEMM, fused bias + (n,l)->(l,n) transpose, f32 out ----------------
__global__ __launch_bounds__(256, 4)
void gemm_out(const short* __restrict__ Attn, const short* __restrict__ Wo,
              const float* __restrict__ bo, float* __restrict__ out) {
    __shared__ short As[8192], Bs[8192];
    const int m0 = blockIdx.y * 128, j0 = blockIdx.x * 128;
    f32x4 acc[4][4];
    #pragma unroll
    for (int a = 0; a < 4; ++a)
        #pragma unroll
        for (int b = 0; b < 4; ++b)
            #pragma unroll
            for (int r = 0; r < 4; ++r) acc[a][b][r] = 0.f;
    gemm128(Attn, Wo, As, Bs, acc, m0, j0);

    const int tid = threadIdx.x, lane = tid & 63, w = tid >> 6;
    const int wr = w >> 1, wc = w & 1;
    #pragma unroll
    for (int mi = 0; mi < 4; ++mi)
        #pragma unroll
        for (int nj = 0; nj < 4; ++nj) {
            int col = j0 + wc * 64 + nj * 16 + (lane & 15);
            #pragma unroll
            for (int r = 0; r < 4; ++r) {
                int row = m0 + wr * 64 + mi * 16 + (lane >> 4) * 4 + r;
                int n = row >> 10, l = row & 1023;
                out[((size_t)(l * 4 + n)) * 2048 + col] = acc[mi][nj][r] + bo[col];
            }
        }
}

// ---------------- flash attention, sliding window [i-512, i], ALiBi ----------------
__global__ __launch_bounds__(256, 2)
void attn_fwd(const short* __restrict__ Qr, const short* __restrict__ Kr,
              const short* __restrict__ Vr, const float* __restrict__ slopes,
              short* __restrict__ Attn) {
    __shared__ short Ks[64 * 128];    // [key][d], XOR-swizzled rows (256B)
    __shared__ short Vts[128 * 64];   // [d][key], XOR-swizzled rows (128B)
    __shared__ short Ps[4][2048];     // per-wave P [32][64], swizzled

    // XCD-locality swizzle: 512 blocks; each XCD gets 8 heads x 8 i0-blocks.
    const int b = blockIdx.x;
    const int nh = (b & 7) * 8 + ((b >> 3) & 7);
    const int i0 = (b >> 6) * 128;
    const int n = nh >> 4, h = nh & 15;
    const short* Qh = Qr + (size_t)nh * (1024 * 128);
    const short* Kh = Kr + (size_t)nh * (1024 * 128);
    const short* Vh = Vr + (size_t)nh * (1024 * 128);
    const float slope = slopes[h];
    const int tid = threadIdx.x, lane = tid & 63, w = tid >> 6;

    s16x8 qf[2][4];
    #pragma unroll
    for (int mi = 0; mi < 2; ++mi)
        #pragma unroll
        for (int kk = 0; kk < 4; ++kk) {
            int row = i0 + w * 32 + mi * 16 + (lane & 15);
            qf[mi][kk] = *reinterpret_cast<const s16x8*>(Qh + (size_t)row * 128 + kk * 32 + (lane >> 4) * 8);
        }

    f32x4 oacc[2][8];
    #pragma unroll
    for (int mi = 0; mi < 2; ++mi)
        #pragma unroll
        for (int dj = 0; dj < 8; ++dj)
            #pragma unroll
            for (int r = 0; r < 4; ++r) oacc[mi][dj][r] = 0.f;
    float mrun[2][4], lrun[2][4];
    #pragma unroll
    for (int mi = 0; mi < 2; ++mi)
        #pragma unroll
        for (int r = 0; r < 4; ++r) { mrun[mi][r] = -1e30f; lrun[mi][r] = 0.f; }

    const int jlo = (i0 >= 512) ? (i0 - 512) : 0;
    const int jhi = i0 + 127;
    for (int j0 = jlo; j0 <= jhi; j0 += 64) {
        #pragma unroll
        for (int q = 0; q < 4; ++q) {
            int rbase = w * 16 + q * 4;
            int rloc = rbase + (lane >> 4);
            int lc = ((lane & 15) ^ (rloc & 7)) << 3;
            GLD16(Kh + (size_t)(j0 + rloc) * 128 + lc, Ks + rbase * 128);
        }
        #pragma unroll
        for (int p = 0; p < 4; ++p) {
            int d0 = (w + p * 4) * 8;
            int jj = j0 + lane;
            i32x4 vv = *reinterpret_cast<const i32x4*>(Vh + (size_t)jj * 128 + d0);
            const short* vs = reinterpret_cast<const short*>(&vv);
            #pragma unroll
            for (int e = 0; e < 8; ++e) {
                int d = d0 + e;
                int byte = d * 128 + ((lane * 2) ^ ((d & 7) << 4));
                *reinterpret_cast<short*>(reinterpret_cast<char*>(Vts) + byte) = vs[e];
            }
        }
        __syncthreads();

        f32x4 sacc[2][4];
        #pragma unroll
        for (int mi = 0; mi < 2; ++mi)
            #pragma unroll
            for (int nj = 0; nj < 4; ++nj)
                #pragma unroll
                for (int r = 0; r < 4; ++r) sacc[mi][nj][r] = 0.f;
        #pragma unroll
        for (int kk = 0; kk < 4; ++kk) {
            s16x8 kf[4];
            #pragma unroll
            for (int nj = 0; nj < 4; ++nj) {
                int kr = nj * 16 + (lane & 15);
                int byte = kr * 256 + ((kk * 64 + (lane >> 4) * 16) ^ ((kr & 7) << 4));
                kf[nj] = *reinterpret_cast<const s16x8*>(reinterpret_cast<const char*>(Ks) + byte);
            }
            #pragma unroll
            for (int mi = 0; mi < 2; ++mi)
                #pragma unroll
                for (int nj = 0; nj < 4; ++nj)
                    sacc[mi][nj] = MFMA16(qf[mi][kk], kf[nj], sacc[mi][nj]);
        }

        #pragma unroll
        for (int mi = 0; mi < 2; ++mi) {
            #pragma unroll
            for (int r = 0; r < 4; ++r) {
                int iq = i0 + w * 32 + mi * 16 + (lane >> 4) * 4 + r;
                float mx = -1e30f;
                #pragma unroll
                for (int nj = 0; nj < 4; ++nj) {
                    int jj = j0 + nj * 16 + (lane & 15);
                    float v = -1e30f;
                    if (jj <= iq && jj >= iq - 512)
                        v = sacc[mi][nj][r] + slope * (float)(jj - iq);
                    sacc[mi][nj][r] = v;
                    mx = fmaxf(mx, v);
                }
                #pragma unroll
                for (int s = 1; s < 16; s <<= 1) mx = fmaxf(mx, __shfl_xor(mx, s, 64));
                float mnew = fmaxf(mrun[mi][r], mx);
                float sf = __expf(mrun[mi][r] - mnew);
                mrun[mi][r] = mnew;
                lrun[mi][r] *= sf;
                #pragma unroll
                for (int dj = 0; dj < 8; ++dj) oacc[mi][dj][r] *= sf;
                float rs = 0.f;
                #pragma unroll
                for (int nj = 0; nj < 4; ++nj) {
                    float v = sacc[mi][nj][r];
                    float p = (v < -1e29f) ? 0.f : __expf(v - mnew);
                    sacc[mi][nj][r] = p;
                    rs += p;
                }
                #pragma unroll
                for (int s = 1; s < 16; s <<= 1) rs += __shfl_xor(rs, s, 64);
                lrun[mi][r] += rs;
            }
        }

        char* Pw = reinterpret_cast<char*>(&Ps[w][0]);
        #pragma unroll
        for (int mi = 0; mi < 2; ++mi)
            #pragma unroll
            for (int nj = 0; nj < 4; ++nj)
                #pragma unroll
                for (int r = 0; r < 4; ++r) {
                    int prow = mi * 16 + (lane >> 4) * 4 + r;
                    int cb = (nj * 16 + (lane & 15)) * 2;
                    int byte = prow * 128 + (cb ^ ((prow & 7) << 4));
                    *reinterpret_cast<short*>(Pw + byte) = f2bf(sacc[mi][nj][r]);
                }

        #pragma unroll
        for (int ks = 0; ks < 2; ++ks) {
            s16x8 pf[2];
            #pragma unroll
            for (int mi = 0; mi < 2; ++mi) {
                int prow = mi * 16 + (lane & 15);
                int byte = prow * 128 + (((ks * 32 + (lane >> 4) * 8) * 2) ^ ((prow & 7) << 4));
                pf[mi] = *reinterpret_cast<const s16x8*>(Pw + byte);
            }
            #pragma unroll
            for (int dj = 0; dj < 8; ++dj) {
                int d = dj * 16 + (lane & 15);
                int byte = d * 128 + (((ks * 32 + (lane >> 4) * 8) * 2) ^ ((d & 7) << 4));
                s16x8 vf = *reinterpret_cast<const s16x8*>(reinterpret_cast<const char*>(Vts) + byte);
                #pragma unroll
                for (int mi = 0; mi < 2; ++mi)
                    oacc[mi][dj] = MFMA16(pf[mi], vf, oacc[mi][dj]);
            }
        }
        __syncthreads();
    }

    #pragma unroll
    for (int mi = 0; mi < 2; ++mi)
        #pragma unroll
        for (int dj = 0; dj < 8; ++dj)
            #pragma unroll
            for (int r = 0; r < 4; ++r) {
                int iq = i0 + w * 32 + mi * 16 + (lane >> 4) * 4 + r;
                int d = dj * 16 + (lane & 15);
                float v = oacc[mi][dj][r] / lrun[mi][r];
                Attn[((size_t)(n * 1024 + iq)) * 2048 + h * 128 + d] = f2bf(v);
            }
}

extern "C" void kernel_launch(void* const* d_in, const int* in_sizes, int n_in,
                              void* d_out, int out_size, void* d_ws, size_t ws_size,
                              hipStream_t stream) {
    const float* x      = (const float*)d_in[0];
    const float* wq     = (const float*)d_in[1];
    const float* bq     = (const float*)d_in[2];
    const float* wkv    = (const float*)d_in[3];
    const float* bkv    = (const float*)d_in[4];
    const float* wo     = (const float*)d_in[5];
    const float* bo     = (const float*)d_in[6];
    const float* slopes = (const float*)d_in[7];
    float* out = (float*)d_out;

    char* ws = (char*)d_ws;
    size_t off = 0;
    auto alloc = [&](size_t bytes) { char* p = ws + off; off += (bytes + 255) & ~(size_t)255; return p; };
    float* ctab = (float*)alloc((size_t)1024 * 64 * 4);
    float* stab = (float*)alloc((size_t)1024 * 64 * 4);
    short* Xb   = (short*)alloc((size_t)4096 * 2048 * 2);
    short* Wqkv = (short*)alloc((size_t)6144 * 2048 * 2);
    short* Wo   = (short*)alloc((size_t)2048 * 2048 * 2);
    short* Qr   = (short*)alloc((size_t)64 * 1024 * 128 * 2);
    short* Kr   = (short*)alloc((size_t)64 * 1024 * 128 * 2);
    short* Vr   = (short*)alloc((size_t)64 * 1024 * 128 * 2);
    short* Attn = (short*)alloc((size_t)4096 * 2048 * 2);

    conv_x<<<2048, 256, 0, stream>>>(x, Xb);
    conv_lin<<<1024, 256, 0, stream>>>(wq, Wqkv, 2048 * 2048 / 4);
    conv_lin<<<2048, 256, 0, stream>>>(wkv, Wqkv + (size_t)2048 * 2048, 4096 * 2048 / 4);
    conv_lin<<<1024, 256, 0, stream>>>(wo, Wo, 2048 * 2048 / 4);
    rope_tab<<<1024, 64, 0, stream>>>(ctab, stab);
    gemm_qkv8<<<dim3(24, 16), 512, 0, stream>>>(Xb, Wqkv, bq, bkv, ctab, stab, Qr, Kr, Vr);
    attn_fwd<<<512, 256, 0, stream>>>(Qr, Kr, Vr, slopes, Attn);
    gemm_out<<<dim3(16, 32), 256, 0, stream>>>(Attn, Wo, bo, out);
}

// Round 14
// 244.816 us; speedup vs baseline: 1.1875x; 1.1875x over previous
//
#include <hip/hip_runtime.h>
#include <hip/hip_bf16.h>

typedef __attribute__((ext_vector_type(4))) float f32x4;
typedef __attribute__((ext_vector_type(8))) short s16x8;
typedef __attribute__((ext_vector_type(4))) short s16x4;
typedef __attribute__((ext_vector_type(4))) int i32x4;

__device__ __forceinline__ short f2bf(float f) {
    union { __hip_bfloat16 h; short s; } u;
    u.h = __float2bfloat16(f);
    return u.s;
}

#define GLD16(g, l) __builtin_amdgcn_global_load_lds((const __attribute__((address_space(1))) void*)(g), (__attribute__((address_space(3))) void*)(l), 16, 0, 0)
#define MFMA16(a, b, c) __builtin_amdgcn_mfma_f32_16x16x32_bf16((a), (b), (c), 0, 0, 0)

// ---------------- conversion kernels ----------------
__global__ void conv_lin(const float* __restrict__ in, short* __restrict__ out, int n4) {
    int i = blockIdx.x * blockDim.x + threadIdx.x;
    int stride = gridDim.x * blockDim.x;
    for (; i < n4; i += stride) {
        float4 v = reinterpret_cast<const float4*>(in)[i];
        s16x4 o;
        o[0] = f2bf(v.x); o[1] = f2bf(v.y); o[2] = f2bf(v.z); o[3] = f2bf(v.w);
        reinterpret_cast<s16x4*>(out)[i] = o;
    }
}

// x[L][N][C] f32 -> Xb[(n*L+l)][C] bf16
__global__ void conv_x(const float* __restrict__ x, short* __restrict__ Xb) {
    const int total = 1024 * 4 * 2048 / 4;
    int i = blockIdx.x * blockDim.x + threadIdx.x;
    int stride = gridDim.x * blockDim.x;
    for (; i < total; i += stride) {
        float4 v = reinterpret_cast<const float4*>(x)[i];
        int c4 = i & 511;          // C/4 = 512
        int n  = (i >> 9) & 3;
        int l  = i >> 11;
        s16x4 o;
        o[0] = f2bf(v.x); o[1] = f2bf(v.y); o[2] = f2bf(v.z); o[3] = f2bf(v.w);
        reinterpret_cast<s16x4*>(Xb)[(n * 1024 + l) * 512 + c4] = o;
    }
}

// cos/sin table for positions W..W+L-1, 64 pair-freqs
__global__ void rope_tab(float* __restrict__ ctab, float* __restrict__ stab) {
    int l = blockIdx.x, t = threadIdx.x;
    float pos = (float)(512 + l);
    float inv = __expf(-9.210340371976184f * ((float)t * (1.0f / 64.0f)));
    float a = pos * inv;
    float s, c;
    sincosf(a, &s, &c);
    ctab[l * 64 + t] = c;
    stab[l * 64 + t] = s;
}

// ---------------- 128x128 bf16 GEMM core (round-1/6 verified structure) ----------------
__device__ __forceinline__ void gemm128(const short* __restrict__ A, const short* __restrict__ B,
                                        short* As, short* Bs, f32x4 acc[4][4], int m0, int j0) {
    const int K = 2048;
    const int tid = threadIdx.x;
    const int lane = tid & 63;
    const int w = tid >> 6;
    const int wr = w >> 1, wc = w & 1;
    const int r8 = lane >> 3;                  // row within 8-row staging group
    const int cc = ((lane & 7) ^ r8) << 3;     // pre-swizzled source col (elems)
    const size_t rowA0 = (size_t)(m0 + w * 32 + r8);
    const size_t rowB0 = (size_t)(j0 + w * 32 + r8);
    for (int kt = 0; kt < K; kt += 64) {
        #pragma unroll
        for (int q = 0; q < 4; ++q) {
            GLD16(A + (rowA0 + q * 8) * K + kt + cc, As + (w * 32 + q * 8) * 64);
            GLD16(B + (rowB0 + q * 8) * K + kt + cc, Bs + (w * 32 + q * 8) * 64);
        }
        __syncthreads();
        #pragma unroll
        for (int kk = 0; kk < 2; ++kk) {
            s16x8 af[4], bfv[4];
            #pragma unroll
            for (int mi = 0; mi < 4; ++mi) {
                int row = wr * 64 + mi * 16 + (lane & 15);
                int byte = row * 128 + ((kk * 64 + (lane >> 4) * 16) ^ ((row & 7) << 4));
                af[mi] = *reinterpret_cast<const s16x8*>(reinterpret_cast<const char*>(As) + byte);
            }
            #pragma unroll
            for (int nj = 0; nj < 4; ++nj) {
                int row = wc * 64 + nj * 16 + (lane & 15);
                int byte = row * 128 + ((kk * 64 + (lane >> 4) * 16) ^ ((row & 7) << 4));
                bfv[nj] = *reinterpret_cast<const s16x8*>(reinterpret_cast<const char*>(Bs) + byte);
            }
            #pragma unroll
            for (int mi = 0; mi < 4; ++mi)
                #pragma unroll
                for (int nj = 0; nj < 4; ++nj)
                    acc[mi][nj] = MFMA16(af[mi], bfv[nj], acc[mi][nj]);
        }
        __syncthreads();
    }
}

// ---------------- QKV GEMM, fused bias + RoPE + scatter ----------------
// Xb[4096][2048] @ Wqkv[6144][2048]^T ; cols [0,2048)=Q, [2048,4096)=K, [4096,6144)=V
__global__ __launch_bounds__(256, 4)
void gemm_qkv(const short* __restrict__ Xb, const short* __restrict__ Wqkv,
              const float* __restrict__ bq, const float* __restrict__ bkv,
              const float* __restrict__ ctab, const float* __restrict__ stab,
              short* __restrict__ Qr, short* __restrict__ Kr, short* __restrict__ Vr) {
    __shared__ short As[8192], Bs[8192];
    const int m0 = blockIdx.y * 128, j0 = blockIdx.x * 128;
    f32x4 acc[4][4];
    #pragma unroll
    for (int a = 0; a < 4; ++a)
        #pragma unroll
        for (int b = 0; b < 4; ++b)
            #pragma unroll
            for (int r = 0; r < 4; ++r) acc[a][b][r] = 0.f;
    gemm128(Xb, Wqkv, As, Bs, acc, m0, j0);

    const int tid = threadIdx.x, lane = tid & 63, w = tid >> 6;
    const int wr = w >> 1, wc = w & 1;
    const int region = j0 >> 11;   // 0:Q 1:K 2:V (blocks never straddle)
    #pragma unroll
    for (int mi = 0; mi < 4; ++mi) {
        #pragma unroll
        for (int nj = 0; nj < 4; ++nj) {
            int col = j0 + wc * 64 + nj * 16 + (lane & 15);
            int h = (col >> 7) & 15;
            int d = col & 127;
            #pragma unroll
            for (int r = 0; r < 4; ++r) {
                int row = m0 + wr * 64 + mi * 16 + (lane >> 4) * 4 + r;
                int n = row >> 10, l = row & 1023;
                float v = acc[mi][nj][r];
                size_t oidx = (((size_t)(n * 16 + h)) * 1024 + l) * 128 + d;
                if (region == 0) {
                    v += bq[col];
                    float other = __shfl_xor(v, 1, 64);
                    float cs = ctab[l * 64 + (d >> 1)];
                    float sn = stab[l * 64 + (d >> 1)];
                    float o = (d & 1) ? (other * sn + v * cs) : (v * cs - other * sn);
                    Qr[oidx] = f2bf(o * 0.08838834764831843f);   // fold SCALE into Q
                } else if (region == 1) {
                    v += bkv[col - 2048];
                    float other = __shfl_xor(v, 1, 64);
                    float cs = ctab[l * 64 + (d >> 1)];
                    float sn = stab[l * 64 + (d >> 1)];
                    float o = (d & 1) ? (other * sn + v * cs) : (v * cs - other * sn);
                    Kr[oidx] = f2bf(o);
                } else {
                    v += bkv[col - 2048];
                    Vr[oidx] = f2bf(v);
                }
            }
        }
    }
}

// ---------------- output GEMM, fused bias + (n,l)->(l,n) transpose, f32 out ----------------
__global__ __launch_bounds__(256, 4)
void gemm_out(const short* __restrict__ Attn, const short* __restrict__ Wo,
              const float* __restrict__ bo, float* __restrict__ out) {
    __shared__ short As[8192], Bs[8192];
    const int m0 = blockIdx.y * 128, j0 = blockIdx.x * 128;
    f32x4 acc[4][4];
    #pragma unroll
    for (int a = 0; a < 4; ++a)
        #pragma unroll
        for (int b = 0; b < 4; ++b)
            #pragma unroll
            for (int r = 0; r < 4; ++r) acc[a][b][r] = 0.f;
    gemm128(Attn, Wo, As, Bs, acc, m0, j0);

    const int tid = threadIdx.x, lane = tid & 63, w = tid >> 6;
    const int wr = w >> 1, wc = w & 1;
    #pragma unroll
    for (int mi = 0; mi < 4; ++mi)
        #pragma unroll
        for (int nj = 0; nj < 4; ++nj) {
            int col = j0 + wc * 64 + nj * 16 + (lane & 15);
            #pragma unroll
            for (int r = 0; r < 4; ++r) {
                int row = m0 + wr * 64 + mi * 16 + (lane >> 4) * 4 + r;
                int n = row >> 10, l = row & 1023;
                out[((size_t)(l * 4 + n)) * 2048 + col] = acc[mi][nj][r] + bo[col];
            }
        }
}

// ---------------- flash attention, sliding window [i-512, i], ALiBi ----------------
__global__ __launch_bounds__(256, 2)
void attn_fwd(const short* __restrict__ Qr, const short* __restrict__ Kr,
              const short* __restrict__ Vr, const float* __restrict__ slopes,
              short* __restrict__ Attn) {
    __shared__ short Ks[64 * 128];    // [key][d], XOR-swizzled rows (256B)
    __shared__ short Vts[128 * 64];   // [d][key], XOR-swizzled rows (128B)
    __shared__ short Ps[4][2048];     // per-wave P [32][64], swizzled

    // XCD-locality swizzle: 512 blocks; each XCD gets 8 heads x 8 i0-blocks.
    const int b = blockIdx.x;
    const int nh = (b & 7) * 8 + ((b >> 3) & 7);
    const int i0 = (b >> 6) * 128;
    const int n = nh >> 4, h = nh & 15;
    const short* Qh = Qr + (size_t)nh * (1024 * 128);
    const short* Kh = Kr + (size_t)nh * (1024 * 128);
    const short* Vh = Vr + (size_t)nh * (1024 * 128);
    const float slope = slopes[h];
    const int tid = threadIdx.x, lane = tid & 63, w = tid >> 6;

    s16x8 qf[2][4];
    #pragma unroll
    for (int mi = 0; mi < 2; ++mi)
        #pragma unroll
        for (int kk = 0; kk < 4; ++kk) {
            int row = i0 + w * 32 + mi * 16 + (lane & 15);
            qf[mi][kk] = *reinterpret_cast<const s16x8*>(Qh + (size_t)row * 128 + kk * 32 + (lane >> 4) * 8);
        }

    f32x4 oacc[2][8];
    #pragma unroll
    for (int mi = 0; mi < 2; ++mi)
        #pragma unroll
        for (int dj = 0; dj < 8; ++dj)
            #pragma unroll
            for (int r = 0; r < 4; ++r) oacc[mi][dj][r] = 0.f;
    float mrun[2][4], lrun[2][4];
    #pragma unroll
    for (int mi = 0; mi < 2; ++mi)
        #pragma unroll
        for (int r = 0; r < 4; ++r) { mrun[mi][r] = -1e30f; lrun[mi][r] = 0.f; }

    const int jlo = (i0 >= 512) ? (i0 - 512) : 0;
    const int jhi = i0 + 127;
    for (int j0 = jlo; j0 <= jhi; j0 += 64) {
        #pragma unroll
        for (int q = 0; q < 4; ++q) {
            int rbase = w * 16 + q * 4;
            int rloc = rbase + (lane >> 4);
            int lc = ((lane & 15) ^ (rloc & 7)) << 3;
            GLD16(Kh + (size_t)(j0 + rloc) * 128 + lc, Ks + rbase * 128);
        }
        #pragma unroll
        for (int p = 0; p < 4; ++p) {
            int d0 = (w + p * 4) * 8;
            int jj = j0 + lane;
            i32x4 vv = *reinterpret_cast<const i32x4*>(Vh + (size_t)jj * 128 + d0);
            const short* vs = reinterpret_cast<const short*>(&vv);
            #pragma unroll
            for (int e = 0; e < 8; ++e) {
                int d = d0 + e;
                int byte = d * 128 + ((lane * 2) ^ ((d & 7) << 4));
                *reinterpret_cast<short*>(reinterpret_cast<char*>(Vts) + byte) = vs[e];
            }
        }
        __syncthreads();

        f32x4 sacc[2][4];
        #pragma unroll
        for (int mi = 0; mi < 2; ++mi)
            #pragma unroll
            for (int nj = 0; nj < 4; ++nj)
                #pragma unroll
                for (int r = 0; r < 4; ++r) sacc[mi][nj][r] = 0.f;
        #pragma unroll
        for (int kk = 0; kk < 4; ++kk) {
            s16x8 kf[4];
            #pragma unroll
            for (int nj = 0; nj < 4; ++nj) {
                int kr = nj * 16 + (lane & 15);
                int byte = kr * 256 + ((kk * 64 + (lane >> 4) * 16) ^ ((kr & 7) << 4));
                kf[nj] = *reinterpret_cast<const s16x8*>(reinterpret_cast<const char*>(Ks) + byte);
            }
            #pragma unroll
            for (int mi = 0; mi < 2; ++mi)
                #pragma unroll
                for (int nj = 0; nj < 4; ++nj)
                    sacc[mi][nj] = MFMA16(qf[mi][kk], kf[nj], sacc[mi][nj]);
        }

        #pragma unroll
        for (int mi = 0; mi < 2; ++mi) {
            #pragma unroll
            for (int r = 0; r < 4; ++r) {
                int iq = i0 + w * 32 + mi * 16 + (lane >> 4) * 4 + r;
                float mx = -1e30f;
                #pragma unroll
                for (int nj = 0; nj < 4; ++nj) {
                    int jj = j0 + nj * 16 + (lane & 15);
                    float v = -1e30f;
                    if (jj <= iq && jj >= iq - 512)
                        v = sacc[mi][nj][r] + slope * (float)(jj - iq);
                    sacc[mi][nj][r] = v;
                    mx = fmaxf(mx, v);
                }
                #pragma unroll
                for (int s = 1; s < 16; s <<= 1) mx = fmaxf(mx, __shfl_xor(mx, s, 64));
                float mnew = fmaxf(mrun[mi][r], mx);
                float sf = __expf(mrun[mi][r] - mnew);
                mrun[mi][r] = mnew;
                lrun[mi][r] *= sf;
                #pragma unroll
                for (int dj = 0; dj < 8; ++dj) oacc[mi][dj][r] *= sf;
                float rs = 0.f;
                #pragma unroll
                for (int nj = 0; nj < 4; ++nj) {
                    float v = sacc[mi][nj][r];
                    float p = (v < -1e29f) ? 0.f : __expf(v - mnew);
                    sacc[mi][nj][r] = p;
                    rs += p;
                }
                #pragma unroll
                for (int s = 1; s < 16; s <<= 1) rs += __shfl_xor(rs, s, 64);
                lrun[mi][r] += rs;
            }
        }

        char* Pw = reinterpret_cast<char*>(&Ps[w][0]);
        #pragma unroll
        for (int mi = 0; mi < 2; ++mi)
            #pragma unroll
            for (int nj = 0; nj < 4; ++nj)
                #pragma unroll
                for (int r = 0; r < 4; ++r) {
                    int prow = mi * 16 + (lane >> 4) * 4 + r;
                    int cb = (nj * 16 + (lane & 15)) * 2;
                    int byte = prow * 128 + (cb ^ ((prow & 7) << 4));
                    *reinterpret_cast<short*>(Pw + byte) = f2bf(sacc[mi][nj][r]);
                }

        #pragma unroll
        for (int ks = 0; ks < 2; ++ks) {
            s16x8 pf[2];
            #pragma unroll
            for (int mi = 0; mi < 2; ++mi) {
                int prow = mi * 16 + (lane & 15);
                int byte = prow * 128 + (((ks * 32 + (lane >> 4) * 8) * 2) ^ ((prow & 7) << 4));
                pf[mi] = *reinterpret_cast<const s16x8*>(Pw + byte);
            }
            #pragma unroll
            for (int dj = 0; dj < 8; ++dj) {
                int d = dj * 16 + (lane & 15);
                int byte = d * 128 + (((ks * 32 + (lane >> 4) * 8) * 2) ^ ((d & 7) << 4));
                s16x8 vf = *reinterpret_cast<const s16x8*>(reinterpret_cast<const char*>(Vts) + byte);
                #pragma unroll
                for (int mi = 0; mi < 2; ++mi)
                    oacc[mi][dj] = MFMA16(pf[mi], vf, oacc[mi][dj]);
            }
        }
        __syncthreads();
    }

    #pragma unroll
    for (int mi = 0; mi < 2; ++mi)
        #pragma unroll
        for (int dj = 0; dj < 8; ++dj)
            #pragma unroll
            for (int r = 0; r < 4; ++r) {
                int iq = i0 + w * 32 + mi * 16 + (lane >> 4) * 4 + r;
                int d = dj * 16 + (lane & 15);
                float v = oacc[mi][dj][r] / lrun[mi][r];
                Attn[((size_t)(n * 1024 + iq)) * 2048 + h * 128 + d] = f2bf(v);
            }
}

extern "C" void kernel_launch(void* const* d_in, const int* in_sizes, int n_in,
                              void* d_out, int out_size, void* d_ws, size_t ws_size,
                              hipStream_t stream) {
    const float* x      = (const float*)d_in[0];
    const float* wq     = (const float*)d_in[1];
    const float* bq     = (const float*)d_in[2];
    const float* wkv    = (const float*)d_in[3];
    const float* bkv    = (const float*)d_in[4];
    const float* wo     = (const float*)d_in[5];
    const float* bo     = (const float*)d_in[6];
    const float* slopes = (const float*)d_in[7];
    float* out = (float*)d_out;

    char* ws = (char*)d_ws;
    size_t off = 0;
    auto alloc = [&](size_t bytes) { char* p = ws + off; off += (bytes + 255) & ~(size_t)255; return p; };
    float* ctab = (float*)alloc((size_t)1024 * 64 * 4);
    float* stab = (float*)alloc((size_t)1024 * 64 * 4);
    short* Xb   = (short*)alloc((size_t)4096 * 2048 * 2);
    short* Wqkv = (short*)alloc((size_t)6144 * 2048 * 2);
    short* Wo   = (short*)alloc((size_t)2048 * 2048 * 2);
    short* Qr   = (short*)alloc((size_t)64 * 1024 * 128 * 2);
    short* Kr   = (short*)alloc((size_t)64 * 1024 * 128 * 2);
    short* Vr   = (short*)alloc((size_t)64 * 1024 * 128 * 2);
    short* Attn = (short*)alloc((size_t)4096 * 2048 * 2);

    conv_x<<<2048, 256, 0, stream>>>(x, Xb);
    conv_lin<<<1024, 256, 0, stream>>>(wq, Wqkv, 2048 * 2048 / 4);
    conv_lin<<<2048, 256, 0, stream>>>(wkv, Wqkv + (size_t)2048 * 2048, 4096 * 2048 / 4);
    conv_lin<<<1024, 256, 0, stream>>>(wo, Wo, 2048 * 2048 / 4);
    rope_tab<<<1024, 64, 0, stream>>>(ctab, stab);
    gemm_qkv<<<dim3(48, 32), 256, 0, stream>>>(Xb, Wqkv, bq, bkv, ctab, stab, Qr, Kr, Vr);
    attn_fwd<<<512, 256, 0, stream>>>(Qr, Kr, Vr, slopes, Attn);
    gemm_out<<<dim3(16, 32), 256, 0, stream>>>(Attn, Wo, bo, out);
}